// Round 1
// baseline (483.539 us; speedup 1.0000x reference)
//
#include <hip/hip_runtime.h>

// Output layout per row: [0..11] = x, [12..77] = size-2 combos,
// [78..297] = size-3, [298..792] = size-4 (lexicographic, matching
// itertools.combinations). Total 793 columns.
#define NCOMBO 781
#define NCOLS  793

struct ComboTable { unsigned short m[NCOMBO]; };

constexpr ComboTable make_combos() {
    ComboTable t{};
    int k = 0;
    for (int i = 0; i < 12; ++i)
        for (int j = i + 1; j < 12; ++j)
            t.m[k++] = (unsigned short)((1u << i) | (1u << j));
    for (int i = 0; i < 12; ++i)
        for (int j = i + 1; j < 12; ++j)
            for (int l = j + 1; l < 12; ++l)
                t.m[k++] = (unsigned short)((1u << i) | (1u << j) | (1u << l));
    for (int i = 0; i < 12; ++i)
        for (int j = i + 1; j < 12; ++j)
            for (int l = j + 1; l < 12; ++l)
                for (int p = l + 1; p < 12; ++p)
                    t.m[k++] = (unsigned short)((1u << i) | (1u << j) |
                                                (1u << l) | (1u << p));
    return t;
}

__constant__ ComboTable g_combos = make_combos();

// Semantics of the left-fold of _drastic_pair over a set S:
//   dp(a,b) = (b==1) ? a : ((a==1) ? b : 0)
// 1.0 is an identity; two non-1 values -> 0, and 0 absorbs (dp(0,c)=0).
// => result = 1.0 if zero non-1 elements, the unique non-1 element if
//    exactly one, else 0.0.
__global__ __launch_bounds__(256)
void Drastic_65970697666732_kernel(const float* __restrict__ x,
                                   float* __restrict__ out,
                                   int nrows) {
    const int row = blockIdx.x;
    if (row >= nrows) return;

    __shared__ float    s_x[12];
    __shared__ unsigned s_no;   // bit c set iff x[row][c] != 1.0f

    const int t = threadIdx.x;
    if (t == 0) {
        const float4* xr4 = reinterpret_cast<const float4*>(x + (size_t)row * 12);
        float4 a = xr4[0], b = xr4[1], c = xr4[2];
        float v[12] = {a.x, a.y, a.z, a.w, b.x, b.y, b.z, b.w, c.x, c.y, c.z, c.w};
        unsigned m = 0;
        #pragma unroll
        for (int i = 0; i < 12; ++i) {
            s_x[i] = v[i];
            if (v[i] != 1.0f) m |= (1u << i);
        }
        s_no = m;
    }
    __syncthreads();

    const unsigned rowno = s_no;
    float* orow = out + (size_t)row * NCOLS;

    #pragma unroll
    for (int it = 0; it < 4; ++it) {
        const int col = t + it * 256;
        if (col < NCOLS) {
            float r;
            if (col < 12) {
                r = s_x[col];
            } else {
                const unsigned no = (unsigned)g_combos.m[col - 12] & rowno;
                const int cnt = __popc(no);
                r = (cnt == 0) ? 1.0f : 0.0f;
                if (cnt == 1) r = s_x[__ffs(no) - 1];   // rare path: exec-skipped
            }
            orow[col] = r;
        }
    }
}

extern "C" void kernel_launch(void* const* d_in, const int* in_sizes, int n_in,
                              void* d_out, int out_size, void* d_ws, size_t ws_size,
                              hipStream_t stream) {
    const float* x = (const float*)d_in[0];
    float* out = (float*)d_out;
    const int nrows = in_sizes[0] / 12;   // 131072
    Drastic_65970697666732_kernel<<<nrows, 256, 0, stream>>>(x, out, nrows);
}

// Round 3
// 459.729 us; speedup vs baseline: 1.0518x; 1.0518x over previous
//
#include <hip/hip_runtime.h>

// Output layout per row: [0..11] = x, [12..77] = size-2 combos,
// [78..297] = size-3, [298..792] = size-4 (lexicographic, matching
// itertools.combinations). Total 793 columns.
#define NCOMBO 781
#define NCOLS  793
#define NROWS  131072

struct ComboTable { unsigned m[NCOMBO]; };

constexpr ComboTable make_combos() {
    ComboTable t{};
    int k = 0;
    for (int i = 0; i < 12; ++i)
        for (int j = i + 1; j < 12; ++j)
            t.m[k++] = (1u << i) | (1u << j);
    for (int i = 0; i < 12; ++i)
        for (int j = i + 1; j < 12; ++j)
            for (int l = j + 1; l < 12; ++l)
                t.m[k++] = (1u << i) | (1u << j) | (1u << l);
    for (int i = 0; i < 12; ++i)
        for (int j = i + 1; j < 12; ++j)
            for (int l = j + 1; l < 12; ++l)
                for (int p = l + 1; p < 12; ++p)
                    t.m[k++] = (1u << i) | (1u << j) | (1u << l) | (1u << p);
    return t;
}

__constant__ ComboTable g_combos = make_combos();

// Fold semantics: dp(a,b) = (b==1) ? a : ((a==1) ? b : 0).
// 1.0 is identity; >=2 non-1 elements -> 0; exactly 1 -> that element.

__device__ __forceinline__ unsigned row_mask(const float* __restrict__ x,
                                             unsigned row) {
    const float4* p = reinterpret_cast<const float4*>(x + (size_t)row * 12);
    float4 a = p[0], b = p[1], c = p[2];
    float v[12] = {a.x, a.y, a.z, a.w, b.x, b.y, b.z, b.w, c.x, c.y, c.z, c.w};
    unsigned m = 0;
    #pragma unroll
    for (int i = 0; i < 12; ++i)
        if (v[i] != 1.0f) m |= (1u << i);
    return m;
}

__global__ __launch_bounds__(256)
void mask_kernel(const float* __restrict__ x, unsigned* __restrict__ mask) {
    const int r = blockIdx.x * 256 + threadIdx.x;
    if (r < NROWS) mask[r] = row_mask(x, r);
}

template <bool USE_WS>
__global__ __launch_bounds__(256)
void emit_kernel(const float* __restrict__ x,
                 const unsigned* __restrict__ mask,
                 float4* __restrict__ out, long n4) {
    const long stride = (long)gridDim.x * 256;
    for (long i = (long)blockIdx.x * 256 + threadIdx.x; i < n4; i += stride) {
        const unsigned e0 = (unsigned)(i * 4);          // < 2^27, fits u32
        unsigned row = e0 / NCOLS;                      // magic-mul div
        unsigned col = e0 - row * NCOLS;
        unsigned m = USE_WS ? mask[row] : row_mask(x, row);
        float res[4];
        #pragma unroll
        for (int j = 0; j < 4; ++j) {
            if (col >= NCOLS) {                         // row crossing (rare)
                col -= NCOLS; ++row;
                m = USE_WS ? mask[row] : row_mask(x, row);
            }
            float v;
            if (col < 12) {
                v = x[(size_t)row * 12 + col];
            } else {
                const unsigned no = g_combos.m[col - 12] & m;
                const int cnt = __popc(no);
                v = (cnt == 0) ? 1.0f : 0.0f;
                if (cnt == 1) v = x[(size_t)row * 12 + (__ffs(no) - 1)];
            }
            res[j] = v; ++col;
        }
        out[i] = make_float4(res[0], res[1], res[2], res[3]);
    }
}

extern "C" void kernel_launch(void* const* d_in, const int* in_sizes, int n_in,
                              void* d_out, int out_size, void* d_ws, size_t ws_size,
                              hipStream_t stream) {
    const float* x = (const float*)d_in[0];
    float4* out = (float4*)d_out;
    const long n4 = (long)out_size / 4;                 // 25,985,024
    const int grid = 2048;

    if (ws_size >= (size_t)NROWS * sizeof(unsigned)) {
        unsigned* mask = (unsigned*)d_ws;
        mask_kernel<<<NROWS / 256, 256, 0, stream>>>(x, mask);
        emit_kernel<true><<<grid, 256, 0, stream>>>(x, mask, out, n4);
    } else {
        emit_kernel<false><<<grid, 256, 0, stream>>>(x, nullptr, out, n4);
    }
}

// Round 4
// 419.452 us; speedup vs baseline: 1.1528x; 1.0960x over previous
//
#include <hip/hip_runtime.h>

// Output layout per row: [0..11] = x, [12..77] = size-2 combos,
// [78..297] = size-3, [298..792] = size-4 (lexicographic = itertools).
#define NCOMBO 781
#define NCOLS  793
#define NROWS  131072

struct ComboTable { unsigned m[NCOMBO]; };

constexpr ComboTable make_combos() {
    ComboTable t{};
    int k = 0;
    for (int i = 0; i < 12; ++i)
        for (int j = i + 1; j < 12; ++j)
            t.m[k++] = (1u << i) | (1u << j);
    for (int i = 0; i < 12; ++i)
        for (int j = i + 1; j < 12; ++j)
            for (int l = j + 1; l < 12; ++l)
                t.m[k++] = (1u << i) | (1u << j) | (1u << l);
    for (int i = 0; i < 12; ++i)
        for (int j = i + 1; j < 12; ++j)
            for (int l = j + 1; l < 12; ++l)
                for (int p = l + 1; p < 12; ++p)
                    t.m[k++] = (1u << i) | (1u << j) | (1u << l) | (1u << p);
    return t;
}

__constant__ ComboTable g_combos = make_combos();

// Fold semantics: dp(a,b) = (b==1) ? a : ((a==1) ? b : 0).
// 1.0 identity; >=2 non-1 elements -> 0; exactly 1 -> that element.
// => with mm = "not-one" bitmask of the row:
//    combo&mm has 0 bits -> 1.0 ; 1 bit -> x[that col] ; else 0.
// Fast path: mm == 0xFFF (no element equals 1.0) -> every combo output is 0,
// no table lookup needed. This is wave-uniform on typical data.

__device__ __forceinline__ unsigned row_mask(const float* __restrict__ x,
                                             unsigned row) {
    const float4* p = reinterpret_cast<const float4*>(x + (size_t)row * 12);
    float4 a = p[0], b = p[1], c = p[2];
    float v[12] = {a.x, a.y, a.z, a.w, b.x, b.y, b.z, b.w, c.x, c.y, c.z, c.w};
    unsigned m = 0;
    #pragma unroll
    for (int i = 0; i < 12; ++i)
        if (v[i] != 1.0f) m |= (1u << i);
    return m;
}

__global__ __launch_bounds__(256)
void mask_kernel(const float* __restrict__ x, unsigned* __restrict__ mask) {
    const int r = blockIdx.x * 256 + threadIdx.x;
    if (r < NROWS) mask[r] = row_mask(x, r);
}

template <bool USE_WS>
__global__ __launch_bounds__(256)
void emit_kernel(const float* __restrict__ x,
                 const unsigned* __restrict__ mask,
                 float4* __restrict__ out, int n4) {
    const int stride = gridDim.x * 256;
    for (int i = blockIdx.x * 256 + threadIdx.x; i < n4; i += stride) {
        const unsigned e0 = (unsigned)i * 4u;           // < 2^27
        const unsigned row = e0 / NCOLS;                // magic-mul div
        const unsigned col = e0 - row * NCOLS;
        const unsigned m0 = USE_WS ? mask[row] : row_mask(x, row);
        // A float4 can straddle a row boundary; fetch next row's mask only then.
        // (Last start is row 131071 / col 789, so row+1 is never OOB here.)
        unsigned m1 = m0;
        if (col + 3u >= NCOLS) m1 = USE_WS ? mask[row + 1] : row_mask(x, row + 1);

        float res[4];
        #pragma unroll
        for (int j = 0; j < 4; ++j) {
            unsigned c = col + j;
            unsigned rw = row;
            unsigned mm = m0;
            if (c >= NCOLS) { c -= NCOLS; rw = row + 1; mm = m1; }
            float v;
            if (c < 12u) {
                v = x[(size_t)rw * 12 + c];             // passthrough columns
            } else if (mm == 0xFFFu) {
                v = 0.0f;                               // fast path: no table read
            } else {
                const unsigned no = g_combos.m[c - 12] & mm;
                const int cnt = __popc(no);
                v = (cnt == 0) ? 1.0f : 0.0f;
                if (cnt == 1) v = x[(size_t)rw * 12 + (__ffs(no) - 1)];
            }
            res[j] = v;
        }
        out[i] = make_float4(res[0], res[1], res[2], res[3]);
    }
}

extern "C" void kernel_launch(void* const* d_in, const int* in_sizes, int n_in,
                              void* d_out, int out_size, void* d_ws, size_t ws_size,
                              hipStream_t stream) {
    const float* x = (const float*)d_in[0];
    float4* out = (float4*)d_out;
    const int n4 = out_size / 4;                        // 25,985,024
    const int grid = 4096;

    if (ws_size >= (size_t)NROWS * sizeof(unsigned)) {
        unsigned* mask = (unsigned*)d_ws;
        mask_kernel<<<NROWS / 256, 256, 0, stream>>>(x, mask);
        emit_kernel<true><<<grid, 256, 0, stream>>>(x, mask, out, n4);
    } else {
        emit_kernel<false><<<grid, 256, 0, stream>>>(x, nullptr, out, n4);
    }
}